// Round 14
// baseline (111.599 us; speedup 1.0000x reference)
//
#include <hip/hip_runtime.h>

typedef unsigned short u16;
typedef __bf16 bf16x8 __attribute__((ext_vector_type(8)));
typedef unsigned short u16x8 __attribute__((ext_vector_type(8)));
typedef float f32x4 __attribute__((ext_vector_type(4)));

union Frag { u16x8 u; bf16x8 b; };

__device__ __forceinline__ u16 f2bf(float f) {
  unsigned u = __builtin_bit_cast(unsigned, f);
  u += 0x7fff + ((u >> 16) & 1);
  return (u16)(u >> 16);
}

__device__ __forceinline__ f32x4 mfma16(bf16x8 a, bf16x8 b, f32x4 c) {
  return __builtin_amdgcn_mfma_f32_16x16x32_bf16(a, b, c, 0, 0, 0);
}

// raw v_exp_f32: computes 2^x
__device__ __forceinline__ float exp2_raw(float x) {
  float r;
  asm("v_exp_f32 %0, %1" : "=v"(r) : "v"(x));
  return r;
}

typedef const __attribute__((address_space(1))) void* as1cv;
typedef __attribute__((address_space(3))) void* as3v;

__device__ __forceinline__ void glds16(const u16* g, u16* l) {
  __builtin_amdgcn_global_load_lds((as1cv)g, (as3v)l, 16, 0, 0);
}

#define FENCE asm volatile("" ::: "memory")

// ------- prep: cast x (blocks 4096..5119) + transpose both weights (0..4095) ---
__global__ __launch_bounds__(256) void prep(const float* __restrict__ x,
                                            u16* __restrict__ xb,
                                            const float* __restrict__ wqkv,
                                            u16* __restrict__ wqkvT,
                                            const float* __restrict__ wout,
                                            u16* __restrict__ woutT) {
  __shared__ float tile[32][33];
  int bid = blockIdx.x;
  int tid = threadIdx.x;
  if (bid >= 4096) {
    int i = (bid - 4096) * 256 + tid;
    const int stride = 1024 * 256;
#pragma unroll
    for (int k = 0; k < 4; ++k) {
      float4 v = ((const float4*)x)[i];
      ushort4 o;
      o.x = f2bf(v.x); o.y = f2bf(v.y); o.z = f2bf(v.z); o.w = f2bf(v.w);
      ((ushort4*)xb)[i] = o;
      i += stride;
    }
    return;
  }
  const float* src; u16* dst; int N;
  if (bid < 3072) { src = wqkv; dst = wqkvT; N = 3072; }
  else            { bid -= 3072; src = wout; dst = woutT; N = 1024; }
  const int K = 1024;
  int tn = N >> 5;
  int bk = bid / tn, bn = bid % tn;
  int k0 = bk << 5, n0 = bn << 5;
  int tx = tid & 31, ty = tid >> 5;
#pragma unroll
  for (int i = 0; i < 4; i++)
    tile[ty + 8 * i][tx] = src[(size_t)(k0 + ty + 8 * i) * N + n0 + tx];
  __syncthreads();
#pragma unroll
  for (int i = 0; i < 4; i++)
    dst[(size_t)(n0 + ty + 8 * i) * K + k0 + tx] = f2bf(tile[tx][ty + 8 * i]);
}

// === QKV GEMM: 256x256 tile, BK=32, 8 waves (2Mx4N), 3-tile LDS ring (96KB),
// ONE raw barrier + ONE counted vmcnt per 32-MFMA K-step (loads span barriers).
// Ledger: stage(t+2)->buf (t+2)%3, last read in step t-1 (2 barriers prior);
// reads of tile t covered by vmcnt(4) at end of step t-1; drain at t=nk-2.
// bc < 8 -> Q/K cols to qkv; bc >= 8 -> V cols to vt2 via per-wave transpose.
__global__ __launch_bounds__(512) void gemm_qkv(const u16* __restrict__ A,
                                                const u16* __restrict__ BT,
                                                u16* __restrict__ C,
                                                u16* __restrict__ vt,
                                                int N, int K, int nbc) {
  __shared__ u16 Al[3][8192];   // [256 rows][32 k] u16 per buf
  __shared__ u16 Bl[3][8192];
  int nwg = gridDim.x;                              // 192
  int bid = blockIdx.x;
  int swz = (bid & 7) * (nwg >> 3) + (bid >> 3);    // bijective, nwg%8==0
  int br = swz / nbc, bc = swz % nbc;               // br 0..15, bc 0..11
  int tid = threadIdx.x;
  int w = tid >> 6, l = tid & 63;
  int lg = l >> 4, lq = l & 15;
  int wr = w >> 2, wc = w & 3;                      // 2M x 4N waves

  f32x4 acc[8][4];
#pragma unroll
  for (int m = 0; m < 8; m++)
#pragma unroll
    for (int n = 0; n < 4; n++)
      acc[m][n] = (f32x4){0.f, 0.f, 0.f, 0.f};

  // staging: wave w covers rows w*16..+16 (op1) and 128+w*16..+16 (op2);
  // lane -> row w*16 + (l>>2), col (l&3)*8. LDS dest wave-uniform + lane*16.
  const u16* Ab = A + (size_t)(br * 256 + w * 16 + (l >> 2)) * K + (l & 3) * 8;
  const u16* Bb = BT + (size_t)(bc * 256 + w * 16 + (l >> 2)) * K + (l & 3) * 8;

  auto stage = [&](int it, int buf) {
    int kt = it * 32;
    glds16(Ab + kt, &Al[buf][w * 512]);
    glds16(Ab + (size_t)128 * K + kt, &Al[buf][4096 + w * 512]);
    glds16(Bb + kt, &Bl[buf][w * 512]);
    glds16(Bb + (size_t)128 * K + kt, &Bl[buf][4096 + w * 512]);
  };

  int nk = K >> 5;   // 32
  stage(0, 0);
  stage(1, 1);
  asm volatile("s_waitcnt vmcnt(4)" ::: "memory");  // tile 0 landed, tile 1 in flight
  FENCE; __builtin_amdgcn_s_barrier(); FENCE;

  int cur = 0;
  for (int it = 0; it < nk; ++it) {
    int b2 = cur + 2; if (b2 >= 3) b2 -= 3;
    if (it + 2 < nk) stage(it + 2, b2);

    Frag a[8], bb[4];
#pragma unroll
    for (int m = 0; m < 8; m++)
      a[m].u = *(const u16x8*)(&Al[cur][(wr * 128 + m * 16 + lq) * 32 + lg * 8]);
#pragma unroll
    for (int n = 0; n < 4; n++)
      bb[n].u = *(const u16x8*)(&Bl[cur][(wc * 64 + n * 16 + lq) * 32 + lg * 8]);
    __builtin_amdgcn_s_setprio(1);
#pragma unroll
    for (int m = 0; m < 8; m++)
#pragma unroll
      for (int n = 0; n < 4; n++)
        acc[m][n] = mfma16(a[m].b, bb[n].b, acc[m][n]);
    __builtin_amdgcn_s_setprio(0);

    if (it + 2 < nk)      asm volatile("s_waitcnt vmcnt(4)" ::: "memory");
    else if (it + 1 < nk) asm volatile("s_waitcnt vmcnt(0)" ::: "memory");
    if (it + 1 < nk) { FENCE; __builtin_amdgcn_s_barrier(); FENCE; }
    cur += 1; if (cur >= 3) cur -= 3;
  }

  int col0 = bc * 256 + wc * 64 + lq;   // + 16n
  if (bc < 8) {
    // Q/K columns: plain bf16 store to qkv
#pragma unroll
    for (int m = 0; m < 8; m++) {
      int row0 = br * 256 + wr * 128 + m * 16 + lg * 4;
#pragma unroll
      for (int n = 0; n < 4; n++)
#pragma unroll
        for (int r = 0; r < 4; r++)
          C[(size_t)(row0 + r) * N + col0 + 16 * n] = f2bf(acc[m][n][r]);
    }
  } else {
    // V columns: per-wave LDS transpose -> vt2[bh][sblk][dh][64e], 1KB stores.
    // All glds16 drained (vmcnt(0) at it=nk-2); barrier before LDS reuse.
    __syncthreads();
    u16* stbuf = &Al[0][0] + w * 4096;   // 8KB per wave, wave-private (64KB<=96KB)
    int hh = (bc - 8) * 4 + wc;          // head index 0..15
    int a_ = l >> 3, bgrp = l & 7;
#pragma unroll
    for (int sb = 0; sb < 2; ++sb) {
      // write fragments: local rows 0..63 = acc m in [sb*4, +4)
#pragma unroll
      for (int mm = 0; mm < 4; mm++)
#pragma unroll
        for (int r = 0; r < 4; r++) {
          int srow = 16 * mm + 4 * lg + r;
          int X = ((srow >> 2) & 7) << 3;
#pragma unroll
          for (int n = 0; n < 4; n++)
            stbuf[srow * 64 + ((16 * n + lq) ^ X)] = f2bf(acc[sb * 4 + mm][n][r]);
        }
      // gather along e-permutation, contiguous 1KB wave-stores
      int s_abs = br * 256 + wr * 128 + sb * 64;
      int bb_ = s_abs >> 11;
      int sblk = (s_abs & 2047) >> 6;
      size_t vbase = ((size_t)(bb_ * 16 + hh) * 32 + sblk) * 4096;
#pragma unroll
      for (int j = 0; j < 8; ++j) {
        int dh = 8 * j + a_;
        u16x8 v;
#pragma unroll
        for (int i = 0; i < 8; ++i) {
          int srow = ((bgrp >> 2) << 5) | (((i >> 2) & 1) << 4) |
                     ((bgrp & 3) << 2) | (i & 3);
          int X = ((srow >> 2) & 7) << 3;
          v[i] = stbuf[srow * 64 + (dh ^ X)];
        }
        *(u16x8*)&vt[vbase + dh * 64 + bgrp * 8] = v;
      }
    }
  }
}

// ------- GEMM2: C[M][N] = A[M][K] * BT[N][K]^T + bias  (fp32 out, swizzled) ----
__global__ __launch_bounds__(256) void gemm_bt(const u16* __restrict__ A,
                                               const u16* __restrict__ BT,
                                               float* __restrict__ Cout,
                                               const float* __restrict__ bias,
                                               int N, int K, int nbc) {
  __shared__ u16 Al[2][128 * 32];
  __shared__ u16 Bl[2][128 * 32];
  int nwg = gridDim.x;
  int bid = blockIdx.x;
  int swz = (bid & 7) * (nwg >> 3) + (bid >> 3);
  int br = swz / nbc, bc = swz % nbc;
  int tid = threadIdx.x;
  int w = tid >> 6, l = tid & 63;
  int lg = l >> 4, lq = l & 15;
  int wr = w >> 1, wc = w & 1;

  f32x4 acc[4][4];
#pragma unroll
  for (int m = 0; m < 4; m++)
#pragma unroll
    for (int n = 0; n < 4; n++)
      acc[m][n] = (f32x4){0.f, 0.f, 0.f, 0.f};

  const u16* Ab = A + (size_t)(br * 128 + 32 * w + (l >> 2)) * K + (l & 3) * 8;
  const u16* Bb = BT + (size_t)(bc * 128 + 32 * w + (l >> 2)) * K + (l & 3) * 8;

  auto stage = [&](int it, int buf) {
    int kt = it * 32;
    u16* ald = &Al[buf][32 * w * 32];
    u16* bld = &Bl[buf][32 * w * 32];
    glds16(Ab + kt, ald);
    glds16(Ab + (size_t)16 * K + kt, ald + 16 * 32);
    glds16(Bb + kt, bld);
    glds16(Bb + (size_t)16 * K + kt, bld + 16 * 32);
  };

  int nk = K >> 5;
  stage(0, 0);
  __syncthreads();

  for (int it = 0; it < nk; ++it) {
    int buf = it & 1;
    if (it + 1 < nk) stage(it + 1, buf ^ 1);

    Frag af[4], bf[4];
#pragma unroll
    for (int m = 0; m < 4; m++)
      af[m].u = *(const u16x8*)(&Al[buf][(64 * wr + 16 * m + lq) * 32 + lg * 8]);
#pragma unroll
    for (int n = 0; n < 4; n++)
      bf[n].u = *(const u16x8*)(&Bl[buf][(64 * wc + 16 * n + lq) * 32 + lg * 8]);
    __builtin_amdgcn_s_setprio(1);
#pragma unroll
    for (int m = 0; m < 4; m++)
#pragma unroll
      for (int n = 0; n < 4; n++)
        acc[m][n] = mfma16(af[m].b, bf[n].b, acc[m][n]);
    __builtin_amdgcn_s_setprio(0);
    __syncthreads();
  }

  int row0 = br * 128 + 64 * wr + lg * 4;
  int col0 = bc * 128 + 64 * wc + lq;
#pragma unroll
  for (int n = 0; n < 4; n++) {
    float bv = bias[col0 + 16 * n];
#pragma unroll
    for (int m = 0; m < 4; m++)
#pragma unroll
      for (int r = 0; r < 4; r++)
        Cout[(size_t)(row0 + 16 * m + r) * N + col0 + 16 * n] = acc[m][n][r] + bv;
  }
}

// ------------------------------ flash attention -------------------------------
// 1024 blocks, one 64-row q-tile each. bh = bid&31 (XCD-L2 locality). g=bid>>5
// -> qb via per-octant bijection {31-g, g-8, 39-g, g-16}: every CU's 4 blocks
// sum to 66 tiles, heaviest first. 4 waves, KVBLK=64, 32 KiB dbuf LDS,
// XOR-swizzled rows, glds16 staging, fixed-reference softmax (m=0).
// Branch-free main loop (diagonal peeled), f32x4 lambda, early V reads.
__global__ __launch_bounds__(256) void flash_attn(const u16* __restrict__ qkv,
                                                  const u16* __restrict__ vt,
                                                  u16* __restrict__ aout) {
  __shared__ __align__(16) u16 pool[2][8192];   // per buf: K[64][64] | V^T[64][64]
  const float SL2E = 0.18033688011112043f;      // 0.125 * log2(e)
  int bid = blockIdx.x;
  int bh = bid & 31;
  int g = bid >> 5;
  int qb = (g < 8) ? (31 - g) : (g < 16) ? (g - 8) : (g < 24) ? (39 - g) : (g - 16);
  int b = bh >> 4, h = bh & 15;
  int tid = threadIdx.x;
  int w = tid >> 6, l = tid & 63;
  int lg = l >> 4, lq = l & 15;
  int q0w = qb * 64 + w * 16;
  int qidx = q0w + lq;

  const size_t rs = 3072;
  int srw = l >> 3;
  int scol = 8 * ((l & 7) ^ srw);
  const u16* kg = qkv + (size_t)(b * 2048) * rs + 1024 + h * 64;
  const u16* vg = vt + (size_t)bh * 32 * 4096;
  int r0 = (w * 2 + 0) * 8 + srw;
  int r1 = (w * 2 + 1) * 8 + srw;
  int swz = (lq & 7) << 3;

  Frag qf0, qf1;
  const u16* qbase = qkv + (size_t)(b * 2048 + q0w + lq) * rs + h * 64 + lg * 8;
  qf0.u = *(const u16x8*)(qbase);
  qf1.u = *(const u16x8*)(qbase + 32);

  f32x4 lam4 = {0.f, 0.f, 0.f, 0.f};
  f32x4 o[4];
#pragma unroll
  for (int d = 0; d < 4; ++d) o[d] = (f32x4){0.f, 0.f, 0.f, 0.f};

  auto stage = [&](int tile, int buf) {
    int kt2 = tile * 64;
    u16* nb = &pool[buf][0];
    glds16(kg + (size_t)(kt2 + r0) * rs + scol, nb + (w * 2 + 0) * 512);
    glds16(kg + (size_t)(kt2 + r1) * rs + scol, nb + (w * 2 + 1) * 512);
    glds16(vg + (size_t)kt2 * 64 + r0 * 64 + scol, nb + 4096 + (w * 2 + 0) * 512);
    glds16(vg + (size_t)kt2 * 64 + r1 * 64 + scol, nb + 4096 + (w * 2 + 1) * 512);
  };

  stage(0, 0);
  __syncthreads();

  for (int t = 0; t < qb; ++t) {
    stage(t + 1, (t + 1) & 1);
    const u16* Kl = &pool[t & 1][0];
    const u16* Vl = &pool[t & 1][4096];

    f32x4 s[4];
    __builtin_amdgcn_s_setprio(1);
#pragma unroll
    for (int sub = 0; sub < 4; ++sub) {
      int row = sub * 16 + lq;
      Frag k0, k1;
      k0.u = *(const u16x8*)(Kl + row * 64 + ((lg * 8) ^ swz));
      k1.u = *(const u16x8*)(Kl + row * 64 + ((32 + lg * 8) ^ swz));
      f32x4 z = {0.f, 0.f, 0.f, 0.f};
      s[sub] = mfma16(k0.b, qf0.b, z);
      s[sub] = mfma16(k1.b, qf1.b, s[sub]);
    }
    __builtin_amdgcn_s_setprio(0);

    Frag vf[4][2];
#pragma unroll
    for (int d = 0; d < 4; ++d) {
      int row = d * 16 + lq;
      vf[d][0].u = *(const u16x8*)(Vl + row * 64 + ((lg * 8) ^ swz));
      vf[d][1].u = *(const u16x8*)(Vl + row * 64 + ((32 + lg * 8) ^ swz));
    }

    Frag pf[2];
#pragma unroll
    for (int hf = 0; hf < 2; ++hf)
#pragma unroll
      for (int r = 0; r < 4; ++r) {
        float p0 = exp2_raw(s[2 * hf][r] * SL2E);
        float p1 = exp2_raw(s[2 * hf + 1][r] * SL2E);
        lam4[r] += p0 + p1;
        pf[hf].b[r] = (__bf16)p0;
        pf[hf].b[4 + r] = (__bf16)p1;
      }

    __builtin_amdgcn_s_setprio(1);
#pragma unroll
    for (int d = 0; d < 4; ++d) {
      o[d] = mfma16(vf[d][0].b, pf[0].b, o[d]);
      o[d] = mfma16(vf[d][1].b, pf[1].b, o[d]);
    }
    __builtin_amdgcn_s_setprio(0);
    __syncthreads();
  }

  { // peeled diagonal tile
    const u16* Kl = &pool[qb & 1][0];
    const u16* Vl = &pool[qb & 1][4096];
    int kt = qb * 64;

    f32x4 s[4];
    __builtin_amdgcn_s_setprio(1);
#pragma unroll
    for (int sub = 0; sub < 4; ++sub) {
      int row = sub * 16 + lq;
      Frag k0, k1;
      k0.u = *(const u16x8*)(Kl + row * 64 + ((lg * 8) ^ swz));
      k1.u = *(const u16x8*)(Kl + row * 64 + ((32 + lg * 8) ^ swz));
      f32x4 z = {0.f, 0.f, 0.f, 0.f};
      s[sub] = mfma16(k0.b, qf0.b, z);
      s[sub] = mfma16(k1.b, qf1.b, s[sub]);
    }
    __builtin_amdgcn_s_setprio(0);

    Frag vf[4][2];
#pragma unroll
    for (int d = 0; d < 4; ++d) {
      int row = d * 16 + lq;
      vf[d][0].u = *(const u16x8*)(Vl + row * 64 + ((lg * 8) ^ swz));
      vf[d][1].u = *(const u16x8*)(Vl + row * 64 + ((32 + lg * 8) ^ swz));
    }

#pragma unroll
    for (int sub = 0; sub < 4; ++sub)
#pragma unroll
      for (int r = 0; r < 4; ++r) {
        int key = kt + sub * 16 + lg * 4 + r;
        if (key > qidx) s[sub][r] = -1e30f;
      }

    Frag pf[2];
#pragma unroll
    for (int hf = 0; hf < 2; ++hf)
#pragma unroll
      for (int r = 0; r < 4; ++r) {
        float p0 = exp2_raw(s[2 * hf][r] * SL2E);
        float p1 = exp2_raw(s[2 * hf + 1][r] * SL2E);
        lam4[r] += p0 + p1;
        pf[hf].b[r] = (__bf16)p0;
        pf[hf].b[4 + r] = (__bf16)p1;
      }

    __builtin_amdgcn_s_setprio(1);
#pragma unroll
    for (int d = 0; d < 4; ++d) {
      o[d] = mfma16(vf[d][0].b, pf[0].b, o[d]);
      o[d] = mfma16(vf[d][1].b, pf[1].b, o[d]);
    }
    __builtin_amdgcn_s_setprio(0);
    __syncthreads();
  }

  float lam = lam4[0] + lam4[1] + lam4[2] + lam4[3];
  lam += __shfl_xor(lam, 16);
  lam += __shfl_xor(lam, 32);
  float inv = 1.0f / lam;

  u16* Ost = &pool[0][0] + w * (16 * 72);
#pragma unroll
  for (int d = 0; d < 4; ++d)
#pragma unroll
    for (int r = 0; r < 4; ++r)
      Ost[lq * 72 + d * 16 + lg * 4 + r] = f2bf(o[d][r] * inv);
  int q = l >> 2, c16 = (l & 3) * 16;
  u16x8 t0, t1;
#pragma unroll
  for (int j = 0; j < 8; j++) { t0[j] = Ost[q * 72 + c16 + j]; t1[j] = Ost[q * 72 + c16 + 8 + j]; }
  u16* orow = aout + (size_t)(b * 2048 + qb * 64 + w * 16 + q) * 1024 + h * 64 + c16;
  *(u16x8*)orow = t0;
  *(u16x8*)(orow + 8) = t1;
}

// ------------------------------- launcher -------------------------------------
extern "C" void kernel_launch(void* const* d_in, const int* in_sizes, int n_in,
                              void* d_out, int out_size, void* d_ws, size_t ws_size,
                              hipStream_t stream) {
  const float* x    = (const float*)d_in[0];
  const float* wqkv = (const float*)d_in[1];
  const float* wout = (const float*)d_in[2];
  const float* bout = (const float*)d_in[3];
  float* out = (float*)d_out;

  char* ws = (char*)d_ws;
  u16* xb    = (u16*)(ws);                    //  8,388,608 B
  u16* wqkvT = (u16*)(ws + 8388608);          //  6,291,456 B
  u16* woutT = (u16*)(ws + 14680064);         //  2,097,152 B
  u16* qkvb  = (u16*)(ws + 16777216);         // 25,165,824 B
  u16* vtb   = (u16*)(ws + 41943040);         //  8,388,608 B
  u16* aoutb = (u16*)(ws + 50331648);         //  8,388,608 B (total 56 MiB)

  prep<<<5120, 256, 0, stream>>>(x, xb, wqkv, wqkvT, wout, woutT);

  // qkv = x @ w_qkv (256^2 tile, 3-buf ring); V third lands directly in vt2
  gemm_qkv<<<(4096 / 256) * (3072 / 256), 512, 0, stream>>>(xb, wqkvT, qkvb, vtb,
                                                            3072, 1024, 3072 / 256);
  flash_attn<<<1024, 256, 0, stream>>>(qkvb, vtb, aoutb);

  // out = attn_out @ w_out + b_out  (fp32 out)
  gemm_bt<<<(4096 / 128) * (1024 / 128), 256, 0, stream>>>(aoutb, woutT, out, bout,
                                                           1024, 1024, 1024 / 128);
}

// Round 15
// 102.154 us; speedup vs baseline: 1.0925x; 1.0925x over previous
//
#include <hip/hip_runtime.h>

typedef unsigned short u16;
typedef __bf16 bf16x8 __attribute__((ext_vector_type(8)));
typedef unsigned short u16x8 __attribute__((ext_vector_type(8)));
typedef float f32x4 __attribute__((ext_vector_type(4)));

union Frag { u16x8 u; bf16x8 b; };

__device__ __forceinline__ u16 f2bf(float f) {
  unsigned u = __builtin_bit_cast(unsigned, f);
  u += 0x7fff + ((u >> 16) & 1);
  return (u16)(u >> 16);
}

__device__ __forceinline__ f32x4 mfma16(bf16x8 a, bf16x8 b, f32x4 c) {
  return __builtin_amdgcn_mfma_f32_16x16x32_bf16(a, b, c, 0, 0, 0);
}

// raw v_exp_f32: computes 2^x
__device__ __forceinline__ float exp2_raw(float x) {
  float r;
  asm("v_exp_f32 %0, %1" : "=v"(r) : "v"(x));
  return r;
}

typedef const __attribute__((address_space(1))) void* as1cv;
typedef __attribute__((address_space(3))) void* as3v;

__device__ __forceinline__ void glds16(const u16* g, u16* l) {
  __builtin_amdgcn_global_load_lds((as1cv)g, (as3v)l, 16, 0, 0);
}

// ------- prep: cast x (blocks 4096..5119) + transpose both weights (0..4095) ---
__global__ __launch_bounds__(256) void prep(const float* __restrict__ x,
                                            u16* __restrict__ xb,
                                            const float* __restrict__ wqkv,
                                            u16* __restrict__ wqkvT,
                                            const float* __restrict__ wout,
                                            u16* __restrict__ woutT) {
  __shared__ float tile[32][33];
  int bid = blockIdx.x;
  int tid = threadIdx.x;
  if (bid >= 4096) {
    int i = (bid - 4096) * 256 + tid;
    const int stride = 1024 * 256;
#pragma unroll
    for (int k = 0; k < 4; ++k) {
      float4 v = ((const float4*)x)[i];
      ushort4 o;
      o.x = f2bf(v.x); o.y = f2bf(v.y); o.z = f2bf(v.z); o.w = f2bf(v.w);
      ((ushort4*)xb)[i] = o;
      i += stride;
    }
    return;
  }
  const float* src; u16* dst; int N;
  if (bid < 3072) { src = wqkv; dst = wqkvT; N = 3072; }
  else            { bid -= 3072; src = wout; dst = woutT; N = 1024; }
  const int K = 1024;
  int tn = N >> 5;
  int bk = bid / tn, bn = bid % tn;
  int k0 = bk << 5, n0 = bn << 5;
  int tx = tid & 31, ty = tid >> 5;
#pragma unroll
  for (int i = 0; i < 4; i++)
    tile[ty + 8 * i][tx] = src[(size_t)(k0 + ty + 8 * i) * N + n0 + tx];
  __syncthreads();
#pragma unroll
  for (int i = 0; i < 4; i++)
    dst[(size_t)(n0 + ty + 8 * i) * K + k0 + tx] = f2bf(tile[tx][ty + 8 * i]);
}

// ============ QKV GEMM (128x128, BK=32, 2-phase dbuf, XCD swizzle) =============
// bc < 16 -> Q/K cols to qkv. bc >= 16 -> V cols to vt2[bh][sblk][dh][64e]
// via a per-wave LDS transpose (wave-private 8KB regions, no cross-wave hazard).
__global__ __launch_bounds__(256) void gemm_qkv(const u16* __restrict__ A,
                                                const u16* __restrict__ BT,
                                                u16* __restrict__ C,
                                                u16* __restrict__ vt,
                                                int N, int K, int nbc) {
  __shared__ u16 Al[2][128 * 32];
  __shared__ u16 Bl[2][128 * 32];
  int nwg = gridDim.x;
  int bid = blockIdx.x;
  int swz = (bid & 7) * (nwg >> 3) + (bid >> 3);   // bijective, nwg%8==0
  int br = swz / nbc, bc = swz % nbc;
  int tid = threadIdx.x;
  int w = tid >> 6, l = tid & 63;
  int lg = l >> 4, lq = l & 15;
  int wr = w >> 1, wc = w & 1;

  f32x4 acc[4][4];
#pragma unroll
  for (int m = 0; m < 4; m++)
#pragma unroll
    for (int n = 0; n < 4; n++)
      acc[m][n] = (f32x4){0.f, 0.f, 0.f, 0.f};

  const u16* Ab = A + (size_t)(br * 128 + 32 * w + (l >> 2)) * K + (l & 3) * 8;
  const u16* Bb = BT + (size_t)(bc * 128 + 32 * w + (l >> 2)) * K + (l & 3) * 8;

  auto stage = [&](int it, int buf) {
    int kt = it * 32;
    u16* ald = &Al[buf][32 * w * 32];
    u16* bld = &Bl[buf][32 * w * 32];
    glds16(Ab + kt, ald);
    glds16(Ab + (size_t)16 * K + kt, ald + 16 * 32);
    glds16(Bb + kt, bld);
    glds16(Bb + (size_t)16 * K + kt, bld + 16 * 32);
  };

  int nk = K >> 5;
  stage(0, 0);
  __syncthreads();

  for (int it = 0; it < nk; ++it) {
    int buf = it & 1;
    if (it + 1 < nk) stage(it + 1, buf ^ 1);

    Frag af[4], bf[4];
#pragma unroll
    for (int m = 0; m < 4; m++)
      af[m].u = *(const u16x8*)(&Al[buf][(64 * wr + 16 * m + lq) * 32 + lg * 8]);
#pragma unroll
    for (int n = 0; n < 4; n++)
      bf[n].u = *(const u16x8*)(&Bl[buf][(64 * wc + 16 * n + lq) * 32 + lg * 8]);
    __builtin_amdgcn_s_setprio(1);
#pragma unroll
    for (int m = 0; m < 4; m++)
#pragma unroll
      for (int n = 0; n < 4; n++)
        acc[m][n] = mfma16(af[m].b, bf[n].b, acc[m][n]);
    __builtin_amdgcn_s_setprio(0);
    __syncthreads();
  }

  int row0 = br * 128 + 64 * wr + lg * 4;
  int col0 = bc * 128 + 64 * wc + lq;
  if (bc < 16) {
#pragma unroll
    for (int n = 0; n < 4; n++)
#pragma unroll
      for (int m = 0; m < 4; m++)
#pragma unroll
        for (int r = 0; r < 4; r++)
          C[(size_t)(row0 + 16 * m + r) * N + col0 + 16 * n] = f2bf(acc[m][n][r]);
  } else {
    // V third: per-wave LDS transpose, then coalesced 1KB stores to vt2.
    u16* stbuf = (w == 0) ? &Al[0][0] : (w == 1) ? &Al[1][0]
               : (w == 2) ? &Bl[0][0] : &Bl[1][0];      // 8KB, wave-private
#pragma unroll
    for (int m = 0; m < 4; m++)
#pragma unroll
      for (int r = 0; r < 4; r++) {
        int srow = 16 * m + 4 * lg + r;
        int X = ((srow >> 2) & 7) << 3;
#pragma unroll
        for (int n = 0; n < 4; n++)
          stbuf[srow * 64 + ((16 * n + lq) ^ X)] = f2bf(acc[m][n][r]);
      }
    int a = l >> 3, bgrp = l & 7;
    int s_base = br * 128 + 64 * wr;
    int bb = s_base >> 11;
    int sblk = (s_base & 2047) >> 6;
    int hh = ((bc - 16) << 1) | wc;
    size_t vbase = ((size_t)(bb * 16 + hh) * 32 + sblk) * 4096;
#pragma unroll
    for (int j = 0; j < 8; ++j) {
      int dh = 8 * j + a;
      u16x8 v;
#pragma unroll
      for (int i = 0; i < 8; ++i) {
        int srow = ((bgrp >> 2) << 5) | (((i >> 2) & 1) << 4) |
                   ((bgrp & 3) << 2) | (i & 3);
        int X = ((srow >> 2) & 7) << 3;
        v[i] = stbuf[srow * 64 + (dh ^ X)];
      }
      *(u16x8*)&vt[vbase + dh * 64 + bgrp * 8] = v;
    }
  }
}

// ------- GEMM2: C[M][N] = A[M][K] * BT[N][K]^T + bias  (fp32 out, swizzled) ----
__global__ __launch_bounds__(256) void gemm_bt(const u16* __restrict__ A,
                                               const u16* __restrict__ BT,
                                               float* __restrict__ Cout,
                                               const float* __restrict__ bias,
                                               int N, int K, int nbc) {
  __shared__ u16 Al[2][128 * 32];
  __shared__ u16 Bl[2][128 * 32];
  int nwg = gridDim.x;
  int bid = blockIdx.x;
  int swz = (bid & 7) * (nwg >> 3) + (bid >> 3);
  int br = swz / nbc, bc = swz % nbc;
  int tid = threadIdx.x;
  int w = tid >> 6, l = tid & 63;
  int lg = l >> 4, lq = l & 15;
  int wr = w >> 1, wc = w & 1;

  f32x4 acc[4][4];
#pragma unroll
  for (int m = 0; m < 4; m++)
#pragma unroll
    for (int n = 0; n < 4; n++)
      acc[m][n] = (f32x4){0.f, 0.f, 0.f, 0.f};

  const u16* Ab = A + (size_t)(br * 128 + 32 * w + (l >> 2)) * K + (l & 3) * 8;
  const u16* Bb = BT + (size_t)(bc * 128 + 32 * w + (l >> 2)) * K + (l & 3) * 8;

  auto stage = [&](int it, int buf) {
    int kt = it * 32;
    u16* ald = &Al[buf][32 * w * 32];
    u16* bld = &Bl[buf][32 * w * 32];
    glds16(Ab + kt, ald);
    glds16(Ab + (size_t)16 * K + kt, ald + 16 * 32);
    glds16(Bb + kt, bld);
    glds16(Bb + (size_t)16 * K + kt, bld + 16 * 32);
  };

  int nk = K >> 5;
  stage(0, 0);
  __syncthreads();

  for (int it = 0; it < nk; ++it) {
    int buf = it & 1;
    if (it + 1 < nk) stage(it + 1, buf ^ 1);

    Frag af[4], bf[4];
#pragma unroll
    for (int m = 0; m < 4; m++)
      af[m].u = *(const u16x8*)(&Al[buf][(64 * wr + 16 * m + lq) * 32 + lg * 8]);
#pragma unroll
    for (int n = 0; n < 4; n++)
      bf[n].u = *(const u16x8*)(&Bl[buf][(64 * wc + 16 * n + lq) * 32 + lg * 8]);
    __builtin_amdgcn_s_setprio(1);
#pragma unroll
    for (int m = 0; m < 4; m++)
#pragma unroll
      for (int n = 0; n < 4; n++)
        acc[m][n] = mfma16(af[m].b, bf[n].b, acc[m][n]);
    __builtin_amdgcn_s_setprio(0);
    __syncthreads();
  }

  int row0 = br * 128 + 64 * wr + lg * 4;
  int col0 = bc * 128 + 64 * wc + lq;
#pragma unroll
  for (int n = 0; n < 4; n++) {
    float bv = bias[col0 + 16 * n];
#pragma unroll
    for (int m = 0; m < 4; m++)
#pragma unroll
      for (int r = 0; r < 4; r++)
        Cout[(size_t)(row0 + 16 * m + r) * N + col0 + 16 * n] = acc[m][n][r] + bv;
  }
}

// ------------------------------ flash attention -------------------------------
// 1024 blocks, one 64-row q-tile each. bh = bid&31 (XCD-L2 locality). g=bid>>5
// -> qb via per-octant bijection {31-g, g-8, 39-g, g-16}: every CU's 4 blocks
// sum to 66 tiles, heaviest first. 4 waves, KVBLK=64, 32 KiB dbuf LDS,
// XOR-swizzled rows, glds16 staging, fixed-reference softmax (m=0).
// Branch-free main loop (diagonal peeled), f32x4 lambda, early V reads.
__global__ __launch_bounds__(256) void flash_attn(const u16* __restrict__ qkv,
                                                  const u16* __restrict__ vt,
                                                  u16* __restrict__ aout) {
  __shared__ __align__(16) u16 pool[2][8192];   // per buf: K[64][64] | V^T[64][64]
  const float SL2E = 0.18033688011112043f;      // 0.125 * log2(e)
  int bid = blockIdx.x;
  int bh = bid & 31;
  int g = bid >> 5;
  int qb = (g < 8) ? (31 - g) : (g < 16) ? (g - 8) : (g < 24) ? (39 - g) : (g - 16);
  int b = bh >> 4, h = bh & 15;
  int tid = threadIdx.x;
  int w = tid >> 6, l = tid & 63;
  int lg = l >> 4, lq = l & 15;
  int q0w = qb * 64 + w * 16;
  int qidx = q0w + lq;

  const size_t rs = 3072;
  int srw = l >> 3;
  int scol = 8 * ((l & 7) ^ srw);
  const u16* kg = qkv + (size_t)(b * 2048) * rs + 1024 + h * 64;
  const u16* vg = vt + (size_t)bh * 32 * 4096;
  int r0 = (w * 2 + 0) * 8 + srw;
  int r1 = (w * 2 + 1) * 8 + srw;
  int swz = (lq & 7) << 3;

  Frag qf0, qf1;
  const u16* qbase = qkv + (size_t)(b * 2048 + q0w + lq) * rs + h * 64 + lg * 8;
  qf0.u = *(const u16x8*)(qbase);
  qf1.u = *(const u16x8*)(qbase + 32);

  f32x4 lam4 = {0.f, 0.f, 0.f, 0.f};
  f32x4 o[4];
#pragma unroll
  for (int d = 0; d < 4; ++d) o[d] = (f32x4){0.f, 0.f, 0.f, 0.f};

  auto stage = [&](int tile, int buf) {
    int kt2 = tile * 64;
    u16* nb = &pool[buf][0];
    glds16(kg + (size_t)(kt2 + r0) * rs + scol, nb + (w * 2 + 0) * 512);
    glds16(kg + (size_t)(kt2 + r1) * rs + scol, nb + (w * 2 + 1) * 512);
    glds16(vg + (size_t)kt2 * 64 + r0 * 64 + scol, nb + 4096 + (w * 2 + 0) * 512);
    glds16(vg + (size_t)kt2 * 64 + r1 * 64 + scol, nb + 4096 + (w * 2 + 1) * 512);
  };

  stage(0, 0);
  __syncthreads();

  // -------- main loop: non-diagonal tiles, branch-free --------
  for (int t = 0; t < qb; ++t) {
    stage(t + 1, (t + 1) & 1);
    const u16* Kl = &pool[t & 1][0];
    const u16* Vl = &pool[t & 1][4096];

    f32x4 s[4];
    __builtin_amdgcn_s_setprio(1);
#pragma unroll
    for (int sub = 0; sub < 4; ++sub) {
      int row = sub * 16 + lq;
      Frag k0, k1;
      k0.u = *(const u16x8*)(Kl + row * 64 + ((lg * 8) ^ swz));
      k1.u = *(const u16x8*)(Kl + row * 64 + ((32 + lg * 8) ^ swz));
      f32x4 z = {0.f, 0.f, 0.f, 0.f};
      s[sub] = mfma16(k0.b, qf0.b, z);
      s[sub] = mfma16(k1.b, qf1.b, s[sub]);
    }
    __builtin_amdgcn_s_setprio(0);

    // issue V fragment reads early: LDS latency hides under the exp2 chain
    Frag vf[4][2];
#pragma unroll
    for (int d = 0; d < 4; ++d) {
      int row = d * 16 + lq;
      vf[d][0].u = *(const u16x8*)(Vl + row * 64 + ((lg * 8) ^ swz));
      vf[d][1].u = *(const u16x8*)(Vl + row * 64 + ((32 + lg * 8) ^ swz));
    }

    Frag pf[2];
#pragma unroll
    for (int hf = 0; hf < 2; ++hf)
#pragma unroll
      for (int r = 0; r < 4; ++r) {
        float p0 = exp2_raw(s[2 * hf][r] * SL2E);
        float p1 = exp2_raw(s[2 * hf + 1][r] * SL2E);
        lam4[r] += p0 + p1;
        pf[hf].b[r] = (__bf16)p0;
        pf[hf].b[4 + r] = (__bf16)p1;
      }

    __builtin_amdgcn_s_setprio(1);
#pragma unroll
    for (int d = 0; d < 4; ++d) {
      o[d] = mfma16(vf[d][0].b, pf[0].b, o[d]);
      o[d] = mfma16(vf[d][1].b, pf[1].b, o[d]);
    }
    __builtin_amdgcn_s_setprio(0);
    __syncthreads();
  }

  // -------- peeled diagonal tile (t = qb): causal mask, no next-stage --------
  {
    const u16* Kl = &pool[qb & 1][0];
    const u16* Vl = &pool[qb & 1][4096];
    int kt = qb * 64;

    f32x4 s[4];
    __builtin_amdgcn_s_setprio(1);
#pragma unroll
    for (int sub = 0; sub < 4; ++sub) {
      int row = sub * 16 + lq;
      Frag k0, k1;
      k0.u = *(const u16x8*)(Kl + row * 64 + ((lg * 8) ^ swz));
      k1.u = *(const u16x8*)(Kl + row * 64 + ((32 + lg * 8) ^ swz));
      f32x4 z = {0.f, 0.f, 0.f, 0.f};
      s[sub] = mfma16(k0.b, qf0.b, z);
      s[sub] = mfma16(k1.b, qf1.b, s[sub]);
    }
    __builtin_amdgcn_s_setprio(0);

    Frag vf[4][2];
#pragma unroll
    for (int d = 0; d < 4; ++d) {
      int row = d * 16 + lq;
      vf[d][0].u = *(const u16x8*)(Vl + row * 64 + ((lg * 8) ^ swz));
      vf[d][1].u = *(const u16x8*)(Vl + row * 64 + ((32 + lg * 8) ^ swz));
    }

#pragma unroll
    for (int sub = 0; sub < 4; ++sub)
#pragma unroll
      for (int r = 0; r < 4; ++r) {
        int key = kt + sub * 16 + lg * 4 + r;
        if (key > qidx) s[sub][r] = -1e30f;
      }

    Frag pf[2];
#pragma unroll
    for (int hf = 0; hf < 2; ++hf)
#pragma unroll
      for (int r = 0; r < 4; ++r) {
        float p0 = exp2_raw(s[2 * hf][r] * SL2E);
        float p1 = exp2_raw(s[2 * hf + 1][r] * SL2E);
        lam4[r] += p0 + p1;
        pf[hf].b[r] = (__bf16)p0;
        pf[hf].b[4 + r] = (__bf16)p1;
      }

    __builtin_amdgcn_s_setprio(1);
#pragma unroll
    for (int d = 0; d < 4; ++d) {
      o[d] = mfma16(vf[d][0].b, pf[0].b, o[d]);
      o[d] = mfma16(vf[d][1].b, pf[1].b, o[d]);
    }
    __builtin_amdgcn_s_setprio(0);
    __syncthreads();   // all waves done reading pool before Ost aliases it
  }

  float lam = lam4[0] + lam4[1] + lam4[2] + lam4[3];
  lam += __shfl_xor(lam, 16);
  lam += __shfl_xor(lam, 32);
  float inv = 1.0f / lam;

  // epilogue: per-wave LDS staging (aliases pool[0]; all waves past final barrier)
  u16* Ost = &pool[0][0] + w * (16 * 72);
#pragma unroll
  for (int d = 0; d < 4; ++d)
#pragma unroll
    for (int r = 0; r < 4; ++r)
      Ost[lq * 72 + d * 16 + lg * 4 + r] = f2bf(o[d][r] * inv);
  int q = l >> 2, c16 = (l & 3) * 16;
  u16x8 t0, t1;
#pragma unroll
  for (int j = 0; j < 8; j++) { t0[j] = Ost[q * 72 + c16 + j]; t1[j] = Ost[q * 72 + c16 + 8 + j]; }
  u16* orow = aout + (size_t)(b * 2048 + qb * 64 + w * 16 + q) * 1024 + h * 64 + c16;
  *(u16x8*)orow = t0;
  *(u16x8*)(orow + 8) = t1;
}

// ------------------------------- launcher -------------------------------------
extern "C" void kernel_launch(void* const* d_in, const int* in_sizes, int n_in,
                              void* d_out, int out_size, void* d_ws, size_t ws_size,
                              hipStream_t stream) {
  const float* x    = (const float*)d_in[0];
  const float* wqkv = (const float*)d_in[1];
  const float* wout = (const float*)d_in[2];
  const float* bout = (const float*)d_in[3];
  float* out = (float*)d_out;

  char* ws = (char*)d_ws;
  u16* xb    = (u16*)(ws);                    //  8,388,608 B
  u16* wqkvT = (u16*)(ws + 8388608);          //  6,291,456 B
  u16* woutT = (u16*)(ws + 14680064);         //  2,097,152 B
  u16* qkvb  = (u16*)(ws + 16777216);         // 25,165,824 B
  u16* vtb   = (u16*)(ws + 41943040);         //  8,388,608 B
  u16* aoutb = (u16*)(ws + 50331648);         //  8,388,608 B (total 56 MiB)

  prep<<<5120, 256, 0, stream>>>(x, xb, wqkv, wqkvT, wout, woutT);

  // qkv = x @ w_qkv; V third lands directly in vt2 (permuted, transposed)
  gemm_qkv<<<(4096 / 128) * (3072 / 128), 256, 0, stream>>>(xb, wqkvT, qkvb, vtb,
                                                            3072, 1024, 3072 / 128);
  flash_attn<<<1024, 256, 0, stream>>>(qkvb, vtb, aoutb);

  // out = attn_out @ w_out + b_out  (fp32 out)
  gemm_bt<<<(4096 / 128) * (1024 / 128), 256, 0, stream>>>(aoutb, woutT, out, bout,
                                                           1024, 1024, 1024 / 128);
}